// Round 3
// baseline (2079.170 us; speedup 1.0000x reference)
//
#include <hip/hip_runtime.h>
#include <hip/hip_bf16.h>

#define BQ 4
#define NQT 1024
#define DM 256
#define HSA 8
#define DHSA 32
#define CAH 8
#define CADH 64
#define CAI 512
#define NPT 4
#define DFFN 1024
#define TT 4
#define HH 64
#define WW 64
#define LVOL 16384

using bf16 = __hip_bfloat16;

__device__ __forceinline__ float b2f(bf16 v) { return __bfloat162float(v); }
__device__ __forceinline__ bf16  f2b(float v) { return __float2bfloat16(v); }
__device__ __forceinline__ float cvt(float v) { return v; }
__device__ __forceinline__ float cvt(bf16 v) { return b2f(v); }

__device__ __forceinline__ float wave_sum64(float v) {
#pragma unroll
  for (int o = 32; o >= 1; o >>= 1) v += __shfl_xor(v, o, 64);
  return v;
}

// ---------------------------------------------------------------------------
// Generic SIMT GEMM: C[M,N] = (A (+A2)) [M,K] @ B [K,N] + bias, f32 accumulate.
// 64x64 tile, 256 threads, 4x4 micro-tile, K-step 16.
// ---------------------------------------------------------------------------
template <int DUAL, int RELU, int OUTBF, typename TA, typename TB>
__global__ __launch_bounds__(256) void gemm_k(
    const TA* __restrict__ A, const TA* __restrict__ A2,
    const TB* __restrict__ Bw, const TB* __restrict__ bias,
    void* __restrict__ Cout, int M, int N, int K) {
  __shared__ __align__(16) float As[16][68];
  __shared__ __align__(16) float Bs[16][64];
  const int tid = threadIdx.x;
  const int tx = tid & 15, ty = tid >> 4;
  const int n0 = blockIdx.x * 64, m0 = blockIdx.y * 64;
  float acc[4][4] = {};
  for (int k0 = 0; k0 < K; k0 += 16) {
#pragma unroll
    for (int i = 0; i < 4; i++) {
      int e = tid + i * 256;
      int m = e >> 4, kk = e & 15;
      size_t ga = (size_t)(m0 + m) * K + (k0 + kk);
      float v = cvt(A[ga]);
      if (DUAL) v += cvt(A2[ga]);
      As[kk][m] = v;
    }
#pragma unroll
    for (int i = 0; i < 4; i++) {
      int e = tid + i * 256;
      int kk = e >> 6, n = e & 63;
      Bs[kk][n] = cvt(Bw[(size_t)(k0 + kk) * N + (n0 + n)]);
    }
    __syncthreads();
#pragma unroll
    for (int kk = 0; kk < 16; kk++) {
      const float4 a4 = *(const float4*)&As[kk][ty * 4];
      const float4 b4 = *(const float4*)&Bs[kk][tx * 4];
      const float av[4] = {a4.x, a4.y, a4.z, a4.w};
      const float bv[4] = {b4.x, b4.y, b4.z, b4.w};
#pragma unroll
      for (int i = 0; i < 4; i++)
#pragma unroll
        for (int j = 0; j < 4; j++) acc[i][j] = fmaf(av[i], bv[j], acc[i][j]);
    }
    __syncthreads();
  }
#pragma unroll
  for (int i = 0; i < 4; i++) {
    int m = m0 + ty * 4 + i;
#pragma unroll
    for (int j = 0; j < 4; j++) {
      int n = n0 + tx * 4 + j;
      float v = acc[i][j] + cvt(bias[n]);
      if (RELU) v = fmaxf(v, 0.0f);
      if (OUTBF)
        ((bf16*)Cout)[(size_t)m * N + n] = f2b(v);
      else
        ((float*)Cout)[(size_t)m * N + n] = v;
    }
  }
}

// ---------------------------------------------------------------------------
// Self-attention (8 heads, dh=32): block = (b, h, 8 query rows).
// ---------------------------------------------------------------------------
__global__ __launch_bounds__(256) void sa_attn_k(
    const float* __restrict__ qh, const float* __restrict__ kh,
    const float* __restrict__ vh, bf16* __restrict__ outp) {
  __shared__ float Qs[8][33];
  __shared__ float Ks[64][33];
  __shared__ float Sc[8][1025];
  __shared__ float inv_den[8];
  const int qc = blockIdx.x;
  const int h = blockIdx.y;
  const int b = blockIdx.z;
  const int tid = threadIdx.x;
  const size_t rowbase = (size_t)(b * NQT) * DM + h * DHSA;
  {
    int r = tid >> 5, d = tid & 31;
    Qs[r][d] = qh[rowbase + (size_t)(qc * 8 + r) * DM + d];
  }
  const float scale = 0.17677669529663687f;  // 1/sqrt(32)
  for (int jt = 0; jt < 16; jt++) {
    __syncthreads();
#pragma unroll
    for (int i = 0; i < 8; i++) {
      int e = tid + i * 256;
      int j = e >> 5, d = e & 31;
      Ks[j][d] = kh[rowbase + (size_t)(jt * 64 + j) * DM + d];
    }
    __syncthreads();
    int r = tid >> 5, jj = tid & 31;
#pragma unroll
    for (int j2 = 0; j2 < 2; j2++) {
      int j = jj * 2 + j2;
      float s = 0.f;
#pragma unroll
      for (int d = 0; d < 32; d++) s = fmaf(Qs[r][d], Ks[j][d], s);
      Sc[r][jt * 64 + j] = s * scale;
    }
  }
  __syncthreads();
  {
    int r = tid >> 5, l = tid & 31;
    float m = -1e30f;
    for (int j = l; j < 1024; j += 32) m = fmaxf(m, Sc[r][j]);
#pragma unroll
    for (int o = 16; o >= 1; o >>= 1) m = fmaxf(m, __shfl_xor(m, o, 32));
    float sum = 0.f;
    for (int j = l; j < 1024; j += 32) {
      float p = expf(Sc[r][j] - m);
      Sc[r][j] = p;
      sum += p;
    }
#pragma unroll
    for (int o = 16; o >= 1; o >>= 1) sum += __shfl_xor(sum, o, 32);
    if (l == 0) inv_den[r] = 1.0f / sum;
  }
  const int r = tid >> 5, d = tid & 31;
  float acc = 0.f;
  for (int jt = 0; jt < 16; jt++) {
    __syncthreads();
#pragma unroll
    for (int i = 0; i < 8; i++) {
      int e = tid + i * 256;
      int j = e >> 5, dd = e & 31;
      Ks[j][dd] = vh[rowbase + (size_t)(jt * 64 + j) * DM + dd];
    }
    __syncthreads();
#pragma unroll 8
    for (int j = 0; j < 64; j++) acc = fmaf(Sc[r][jt * 64 + j], Ks[j][d], acc);
  }
  acc *= inv_den[r];
  outp[rowbase + (size_t)(qc * 8 + r) * DM + d] = f2b(acc);
}

// ---------------------------------------------------------------------------
// ref = sigmoid(x1 @ Wref + bref), off = x1 @ Woff + boff  (per query row)
// ---------------------------------------------------------------------------
__global__ __launch_bounds__(128) void refoff_k(
    const float* __restrict__ x1, const float* __restrict__ Wref,
    const float* __restrict__ bref, const float* __restrict__ Woff,
    const float* __restrict__ boff, float* __restrict__ refb,
    float* __restrict__ offb) {
  __shared__ float xs[256];
  const int row = blockIdx.x;
  const int tid = threadIdx.x;
  xs[tid] = x1[(size_t)row * DM + tid];
  xs[tid + 128] = x1[(size_t)row * DM + tid + 128];
  __syncthreads();
  if (tid < 3) {
    float s = bref[tid];
    for (int d = 0; d < 256; d++) s = fmaf(xs[d], Wref[d * 3 + tid], s);
    refb[(size_t)row * 3 + tid] = 1.0f / (1.0f + expf(-s));
  } else if (tid < 99) {
    int o = tid - 3;
    float s = boff[o];
    for (int d = 0; d < 256; d++) s = fmaf(xs[d], Woff[d * 96 + o], s);
    offb[(size_t)row * 96 + o] = s;
  }
}

// ---------------------------------------------------------------------------
// Shared trilinear corner computation for one (bn, h).
// ---------------------------------------------------------------------------
__device__ __forceinline__ void calc_corners(
    const float* __restrict__ refb, const float* __restrict__ offb, int bn,
    int h, int (&idxs)[NPT][8], float (&wts)[NPT][8]) {
  const float rt = refb[bn * 3 + 0], ry = refb[bn * 3 + 1], rx = refb[bn * 3 + 2];
  const float* ofp = &offb[(size_t)bn * 96 + h * 12];
#pragma unroll
  for (int p = 0; p < NPT; p++) {
    float lt = rt + ofp[p * 3 + 0] * 0.5f;      // OFFSET_SCALE / T
    float ly = ry + ofp[p * 3 + 1] * 0.03125f;  // OFFSET_SCALE / H
    float lx = rx + ofp[p * 3 + 2] * 0.03125f;  // OFFSET_SCALE / W
    float pt = fminf(fmaxf(lt, 0.f), 1.f) * (TT - 1);
    float py = fminf(fmaxf(ly, 0.f), 1.f) * (HH - 1);
    float px = fminf(fmaxf(lx, 0.f), 1.f) * (WW - 1);
    float f0t = floorf(pt), f0y = floorf(py), f0x = floorf(px);
    float frt = pt - f0t, fry = py - f0y, frx = px - f0x;
    int t0 = (int)f0t, y0 = (int)f0y, x0 = (int)f0x;
    int t1 = min(t0 + 1, TT - 1), y1 = min(y0 + 1, HH - 1), x1 = min(x0 + 1, WW - 1);
    float wt0 = 1.f - frt, wy0 = 1.f - fry, wx0 = 1.f - frx;
#pragma unroll
    for (int c = 0; c < 8; c++) {
      int dt = c >> 2, dy = (c >> 1) & 1, dx = c & 1;
      int ct = dt ? t1 : t0, cy = dy ? y1 : y0, cx = dx ? x1 : x0;
      idxs[p][c] = ct * (HH * WW) + cy * WW + cx;
      wts[p][c] = (dt ? frt : wt0) * (dy ? fry : wy0) * (dx ? frx : wx0);
    }
  }
}

// ---------------------------------------------------------------------------
// Sample k-volume at the 4 points, dot with q -> 4 logits into slots.
// One wave per (b,n,h); lane = channel.
// ---------------------------------------------------------------------------
__global__ __launch_bounds__(256) void ca_logits_k(
    const float* __restrict__ qh, const float* __restrict__ refb,
    const float* __restrict__ offb, const bf16* __restrict__ vol,
    float* __restrict__ logits, int slot) {
  const int wid = (blockIdx.x * blockDim.x + threadIdx.x) >> 6;  // 0..32767
  const int lane = threadIdx.x & 63;
  const int h = wid & 7;
  const int bn = wid >> 3;  // 0..4095
  const int b = bn >> 10;
  const float q = qh[(size_t)bn * CAI + h * CADH + lane];
  int idxs[NPT][8];
  float wts[NPT][8];
  calc_corners(refb, offb, bn, h, idxs, wts);
  const size_t volbase = (size_t)b * LVOL * CAI + h * CADH + lane;
  float* lp = logits + ((size_t)bn * CAH + h) * 8 + slot;
#pragma unroll
  for (int p = 0; p < NPT; p++) {
    float ks = 0.f;
#pragma unroll
    for (int c = 0; c < 8; c++)
      ks = fmaf(wts[p][c], b2f(vol[volbase + (size_t)idxs[p][c] * CAI]), ks);
    float li = wave_sum64(q * ks) * 0.125f;  // 1/sqrt(64)
    if (lane == p) lp[p] = li;
  }
}

// ---------------------------------------------------------------------------
// Joint softmax over the 8 logits (4 img + 4 flow) per (bn, h), in place.
// ---------------------------------------------------------------------------
__global__ __launch_bounds__(256) void ca_softmax_k(float* __restrict__ logits) {
  const int i = blockIdx.x * blockDim.x + threadIdx.x;  // 0..32767
  float* p = logits + (size_t)i * 8;
  float v[8], m = -1e30f;
#pragma unroll
  for (int j = 0; j < 8; j++) { v[j] = p[j]; m = fmaxf(m, v[j]); }
  float s = 0.f;
#pragma unroll
  for (int j = 0; j < 8; j++) { v[j] = expf(v[j] - m); s += v[j]; }
  const float inv = 1.0f / s;
#pragma unroll
  for (int j = 0; j < 8; j++) p[j] = v[j] * inv;
}

// ---------------------------------------------------------------------------
// Sample v-volume, weight by attn slots, accumulate. FIRST pass overwrites the
// f32 accumulator; second pass adds and emits bf16.
// ---------------------------------------------------------------------------
template <int FIRST>
__global__ __launch_bounds__(256) void ca_acc_k(
    const float* __restrict__ refb, const float* __restrict__ offb,
    const bf16* __restrict__ vol, const float* __restrict__ attn,
    float* __restrict__ acc, bf16* __restrict__ outp, int slot) {
  const int wid = (blockIdx.x * blockDim.x + threadIdx.x) >> 6;
  const int lane = threadIdx.x & 63;
  const int h = wid & 7;
  const int bn = wid >> 3;
  const int b = bn >> 10;
  int idxs[NPT][8];
  float wts[NPT][8];
  calc_corners(refb, offb, bn, h, idxs, wts);
  const size_t volbase = (size_t)b * LVOL * CAI + h * CADH + lane;
  const float* ap = attn + ((size_t)bn * CAH + h) * 8 + slot;
  const size_t off = (size_t)bn * CAI + h * CADH + lane;
  float a = FIRST ? 0.f : acc[off];
#pragma unroll
  for (int p = 0; p < NPT; p++) {
    float vs = 0.f;
#pragma unroll
    for (int c = 0; c < 8; c++)
      vs = fmaf(wts[p][c], b2f(vol[volbase + (size_t)idxs[p][c] * CAI]), vs);
    a = fmaf(ap[p], vs, a);
  }
  if (FIRST)
    acc[off] = a;
  else
    outp[off] = f2b(a);
}

// ---------------------------------------------------------------------------
// LayerNorm over 256 dims of (res + x); one wave per row. Residual is f32.
// WF writes f32 `of`; WB writes bf16 `ob`.
// ---------------------------------------------------------------------------
template <int WF, int WB>
__global__ __launch_bounds__(256) void ln_k(
    const float* __restrict__ resv, const float* __restrict__ x,
    const float* __restrict__ g, const float* __restrict__ bb,
    float* __restrict__ of, bf16* __restrict__ ob) {
  const int row = (blockIdx.x * blockDim.x + threadIdx.x) >> 6;
  const int lane = threadIdx.x & 63;
  const size_t base = (size_t)row * DM;
  float v[4];
#pragma unroll
  for (int i = 0; i < 4; i++) {
    int d = lane + i * 64;
    v[i] = resv[base + d] + x[base + d];
  }
  float s = wave_sum64(v[0] + v[1] + v[2] + v[3]);
  const float mean = s * (1.0f / 256.0f);
  float vs = 0.f;
#pragma unroll
  for (int i = 0; i < 4; i++) { float d0 = v[i] - mean; vs = fmaf(d0, d0, vs); }
  vs = wave_sum64(vs);
  const float rstd = rsqrtf(vs * (1.0f / 256.0f) + 1e-5f);
#pragma unroll
  for (int i = 0; i < 4; i++) {
    int d = lane + i * 64;
    float o = (v[i] - mean) * rstd * g[d] + bb[d];
    if (WF) of[base + d] = o;
    if (WB) ob[base + d] = f2b(o);
  }
}

extern "C" void kernel_launch(void* const* d_in, const int* in_sizes, int n_in,
                              void* d_out, int out_size, void* d_ws,
                              size_t ws_size, hipStream_t stream) {
  const float* query = (const float*)d_in[0];
  const float* qpos = (const float*)d_in[1];
  const float* img = (const float*)d_in[2];
  const float* flow = (const float*)d_in[3];
  const float* pos = (const float*)d_in[4];
  const float* sa_Wq = (const float*)d_in[6];
  const float* sa_Wk = (const float*)d_in[7];
  const float* sa_Wv = (const float*)d_in[8];
  const float* sa_Wo = (const float*)d_in[9];
  const float* sa_bq = (const float*)d_in[10];
  const float* sa_bk = (const float*)d_in[11];
  const float* sa_bv = (const float*)d_in[12];
  const float* sa_bo = (const float*)d_in[13];
  const float* ln1_b = (const float*)d_in[14];
  const float* ln2_b = (const float*)d_in[15];
  const float* ln3_b = (const float*)d_in[16];
  const float* ln1_g = (const float*)d_in[17];
  const float* ln2_g = (const float*)d_in[18];
  const float* ln3_g = (const float*)d_in[19];
  const float* ca_Wq = (const float*)d_in[20];
  const float* ca_bq = (const float*)d_in[21];
  const float* ca_Wk = (const float*)d_in[22];
  const float* ca_bk = (const float*)d_in[23];
  const float* ca_Wv = (const float*)d_in[24];
  const float* ca_bv = (const float*)d_in[25];
  const float* ca_Wref = (const float*)d_in[26];
  const float* ca_bref = (const float*)d_in[27];
  const float* ca_Woff = (const float*)d_in[28];
  const float* ca_boff = (const float*)d_in[29];
  const float* ca_Wo = (const float*)d_in[30];
  const float* ca_bo = (const float*)d_in[31];
  const float* ffn_W1 = (const float*)d_in[32];
  const float* ffn_b1 = (const float*)d_in[33];
  const float* ffn_W2 = (const float*)d_in[34];
  const float* ffn_b2 = (const float*)d_in[35];

  const int MQ = BQ * NQT;   // 4096
  const int MV = BQ * LVOL;  // 65536
  const size_t MB = 1024 * 1024;

  // region0 (64 MB) is time-shared:
  //   SA phase:   qh(4) kh(4) vh(4) sa_att(2) sa_proj(4)
  //   CA phase:   the single bf16 volume buffer (64 MB), reused 4x
  //   post-CA:    ca_o(4) x2_f(4) x2_b(2) ffn_h(8) ffn_o(4)
  char* r0 = (char*)d_ws;
  char* w = r0 + 64 * MB;
  auto alloc = [&](size_t n) {
    char* p = w;
    w += (n + 255) & ~(size_t)255;
    return p;
  };
  float* x1_f = (float*)alloc((size_t)MQ * DM * 4);
  bf16* x1_b = (bf16*)alloc((size_t)MQ * DM * 2);
  float* ca_qh = (float*)alloc((size_t)MQ * CAI * 4);
  float* refb = (float*)alloc((size_t)MQ * 3 * 4);
  float* offb = (float*)alloc((size_t)MQ * 96 * 4);
  float* logits = (float*)alloc((size_t)MQ * CAH * 8 * 4);
  float* ca_acc = (float*)alloc((size_t)MQ * CAI * 4);
  bf16* ca_samp = (bf16*)alloc((size_t)MQ * CAI * 2);
  if ((size_t)(w - (char*)d_ws) > ws_size) return;  // graceful fail (diagnostic)

  // SA-phase overlays in region0
  float* qh_sa = (float*)(r0 + 0 * MB);
  float* kh_sa = (float*)(r0 + 4 * MB);
  float* vh_sa = (float*)(r0 + 8 * MB);
  bf16* sa_att = (bf16*)(r0 + 12 * MB);
  float* sa_proj = (float*)(r0 + 14 * MB);
  // CA volume overlay
  bf16* vol = (bf16*)r0;  // 64 MB
  // post-CA overlays
  float* ca_o = (float*)(r0 + 0 * MB);
  float* x2_f = (float*)(r0 + 4 * MB);
  bf16* x2_b = (bf16*)(r0 + 8 * MB);
  bf16* ffn_h = (bf16*)(r0 + 10 * MB);
  float* ffn_o = (float*)(r0 + 18 * MB);

  dim3 blk(256);
  // --- self-attention ---
  gemm_k<1, 0, 0><<<dim3(DM / 64, MQ / 64), blk, 0, stream>>>(query, qpos, sa_Wq, sa_bq, (void*)qh_sa, MQ, DM, DM);
  gemm_k<1, 0, 0><<<dim3(DM / 64, MQ / 64), blk, 0, stream>>>(query, qpos, sa_Wk, sa_bk, (void*)kh_sa, MQ, DM, DM);
  gemm_k<0, 0, 0><<<dim3(DM / 64, MQ / 64), blk, 0, stream>>>(query, query, sa_Wv, sa_bv, (void*)vh_sa, MQ, DM, DM);
  sa_attn_k<<<dim3(128, 8, 4), blk, 0, stream>>>(qh_sa, kh_sa, vh_sa, sa_att);
  gemm_k<0, 0, 0><<<dim3(DM / 64, MQ / 64), blk, 0, stream>>>(sa_att, sa_att, sa_Wo, sa_bo, (void*)sa_proj, MQ, DM, DM);
  ln_k<1, 1><<<dim3(MQ / 4), blk, 0, stream>>>(query, sa_proj, ln1_g, ln1_b, x1_f, x1_b);
  // --- deformable cross-attention (single shared volume buffer) ---
  gemm_k<0, 0, 0><<<dim3(CAI / 64, MQ / 64), blk, 0, stream>>>(x1_b, x1_b, ca_Wq, ca_bq, (void*)ca_qh, MQ, CAI, DM);
  refoff_k<<<dim3(MQ), dim3(128), 0, stream>>>(x1_f, ca_Wref, ca_bref, ca_Woff, ca_boff, refb, offb);
  gemm_k<1, 0, 1><<<dim3(CAI / 64, MV / 64), blk, 0, stream>>>(pos, img, ca_Wk, ca_bk, (void*)vol, MV, CAI, DM);
  ca_logits_k<<<dim3(8192), blk, 0, stream>>>(ca_qh, refb, offb, vol, logits, 0);
  gemm_k<1, 0, 1><<<dim3(CAI / 64, MV / 64), blk, 0, stream>>>(pos, flow, ca_Wk, ca_bk, (void*)vol, MV, CAI, DM);
  ca_logits_k<<<dim3(8192), blk, 0, stream>>>(ca_qh, refb, offb, vol, logits, 4);
  ca_softmax_k<<<dim3(128), blk, 0, stream>>>(logits);
  gemm_k<0, 0, 1><<<dim3(CAI / 64, MV / 64), blk, 0, stream>>>(img, img, ca_Wv, ca_bv, (void*)vol, MV, CAI, DM);
  ca_acc_k<1><<<dim3(8192), blk, 0, stream>>>(refb, offb, vol, logits, ca_acc, nullptr, 0);
  gemm_k<0, 0, 1><<<dim3(CAI / 64, MV / 64), blk, 0, stream>>>(flow, flow, ca_Wv, ca_bv, (void*)vol, MV, CAI, DM);
  ca_acc_k<0><<<dim3(8192), blk, 0, stream>>>(refb, offb, vol, logits, ca_acc, ca_samp, 4);
  gemm_k<0, 0, 0><<<dim3(DM / 64, MQ / 64), blk, 0, stream>>>(ca_samp, ca_samp, ca_Wo, ca_bo, (void*)ca_o, MQ, DM, CAI);
  ln_k<1, 1><<<dim3(MQ / 4), blk, 0, stream>>>(x1_f, ca_o, ln2_g, ln2_b, x2_f, x2_b);
  // --- FFN ---
  gemm_k<0, 1, 1><<<dim3(DFFN / 64, MQ / 64), blk, 0, stream>>>(x2_b, x2_b, ffn_W1, ffn_b1, (void*)ffn_h, MQ, DFFN, DM);
  gemm_k<0, 0, 0><<<dim3(DM / 64, MQ / 64), blk, 0, stream>>>(ffn_h, ffn_h, ffn_W2, ffn_b2, (void*)ffn_o, MQ, DM, DFFN);
  ln_k<1, 0><<<dim3(MQ / 4), blk, 0, stream>>>(x2_f, ffn_o, ln3_g, ln3_b, (float*)d_out, nullptr);
}

// Round 4
// 1206.791 us; speedup vs baseline: 1.7229x; 1.7229x over previous
//
#include <hip/hip_runtime.h>
#include <hip/hip_bf16.h>

#define BQ 4
#define NQT 1024
#define DM 256
#define HSA 8
#define DHSA 32
#define CAH 8
#define CADH 64
#define CAI 512
#define NPT 4
#define DFFN 1024
#define TT 4
#define HH 64
#define WW 64
#define LVOL 16384

using bf16 = __hip_bfloat16;
typedef __attribute__((ext_vector_type(4))) float fx4;
typedef __attribute__((ext_vector_type(8))) short s8v;
typedef __attribute__((ext_vector_type(4))) short s4v;

__device__ __forceinline__ float b2f(bf16 v) { return __bfloat162float(v); }
__device__ __forceinline__ bf16  f2b(float v) { return __float2bfloat16(v); }
__device__ __forceinline__ short f2bs(float v) {
  bf16 b = __float2bfloat16(v);
  return *reinterpret_cast<short*>(&b);
}

__device__ __forceinline__ float wave_sum64(float v) {
#pragma unroll
  for (int o = 32; o >= 1; o >>= 1) v += __shfl_xor(v, o, 64);
  return v;
}

// ---------------------------------------------------------------------------
// Weight pre-transpose + bf16 cast: W[K][N] f32 -> Wt[N][K] bf16.
// K = 1<<KSH. One thread per element.
// ---------------------------------------------------------------------------
template <int KSH>
__global__ __launch_bounds__(256) void wtrans_k(const float* __restrict__ W,
                                               short* __restrict__ Wt, int N) {
  const int i = blockIdx.x * 256 + threadIdx.x;  // i = n*K + k
  const int k = i & ((1 << KSH) - 1);
  const int n = i >> KSH;
  Wt[i] = f2bs(W[(size_t)k * N + n]);
}

// ---------------------------------------------------------------------------
// MFMA GEMM: C[M,N] = (A (+A2))[M,K] @ W[K,N] + bias.
// A,A2: f32 row-major. Wt: bf16 pre-transposed [N][K]. f32 accumulate.
// Tile 128x128, BK=32, 256 threads = 4 waves of 64x64.
// mfma_f32_16x16x32_bf16; A/B frag: [outer=lane&15][k=quad*8+j];
// C/D frag: col=lane&15, row=quad*4+reg  [verified layouts].
// ---------------------------------------------------------------------------
template <int DUAL, int RELU, int OUTBF>
__global__ __launch_bounds__(256) void mgemm_k(
    const float* __restrict__ A, const float* __restrict__ A2,
    const short* __restrict__ Wt, const float* __restrict__ bias,
    void* __restrict__ Cout, int M, int N, int K) {
  __shared__ short As[128 * 40];  // [m][k], rows padded to 40 (80 B)
  __shared__ short Bs[128 * 40];  // [n][k], same padding
  const int tid = threadIdx.x;
  const int lane = tid & 63, w = tid >> 6;
  const int wr = w >> 1, wc = w & 1;
  const int lm = lane & 15, quad = lane >> 4;
  const int m0 = blockIdx.y * 128, n0 = blockIdx.x * 128;
  fx4 acc[4][4] = {};
  for (int k0 = 0; k0 < K; k0 += 32) {
    // stage A: 128 rows x 32 k, f32(+f32) -> bf16
#pragma unroll
    for (int i = 0; i < 4; i++) {
      int m = (tid >> 3) + i * 32;
      int k = (tid & 7) * 4;
      const float4 av = *(const float4*)&A[(size_t)(m0 + m) * K + k0 + k];
      float x0 = av.x, x1 = av.y, x2 = av.z, x3 = av.w;
      if (DUAL) {
        const float4 a2 = *(const float4*)&A2[(size_t)(m0 + m) * K + k0 + k];
        x0 += a2.x; x1 += a2.y; x2 += a2.z; x3 += a2.w;
      }
      s4v sv = {f2bs(x0), f2bs(x1), f2bs(x2), f2bs(x3)};
      *(s4v*)&As[m * 40 + k] = sv;
    }
    // stage B: 128 n-rows x 32 k from Wt (already bf16, contiguous in k)
#pragma unroll
    for (int i = 0; i < 2; i++) {
      int unit = tid + i * 256;
      int n = unit >> 2, c = unit & 3;
      s8v bv = *(const s8v*)&Wt[(size_t)(n0 + n) * K + k0 + c * 8];
      *(s8v*)&Bs[n * 40 + c * 8] = bv;
    }
    __syncthreads();
    s8v af[4], bfr[4];
#pragma unroll
    for (int f = 0; f < 4; f++) {
      af[f] = *(s8v*)&As[(wr * 64 + f * 16 + lm) * 40 + quad * 8];
      bfr[f] = *(s8v*)&Bs[(wc * 64 + f * 16 + lm) * 40 + quad * 8];
    }
#pragma unroll
    for (int fm = 0; fm < 4; fm++)
#pragma unroll
      for (int fn = 0; fn < 4; fn++)
        acc[fm][fn] = __builtin_amdgcn_mfma_f32_16x16x32_bf16(
            af[fm], bfr[fn], acc[fm][fn], 0, 0, 0);
    __syncthreads();
  }
#pragma unroll
  for (int fn = 0; fn < 4; fn++) {
    const int n = n0 + wc * 64 + fn * 16 + lm;
    const float bb = bias[n];
#pragma unroll
    for (int fm = 0; fm < 4; fm++) {
      const int mbase = m0 + wr * 64 + fm * 16 + quad * 4;
#pragma unroll
      for (int r = 0; r < 4; r++) {
        float v = acc[fm][fn][r] + bb;
        if (RELU) v = fmaxf(v, 0.0f);
        const size_t off = (size_t)(mbase + r) * N + n;
        if (OUTBF)
          ((bf16*)Cout)[off] = f2b(v);
        else
          ((float*)Cout)[off] = v;
      }
    }
  }
}

// ---------------------------------------------------------------------------
// Self-attention (8 heads, dh=32): block = (b, h, 8 query rows). f32 out.
// ---------------------------------------------------------------------------
__global__ __launch_bounds__(256) void sa_attn_k(
    const float* __restrict__ qh, const float* __restrict__ kh,
    const float* __restrict__ vh, float* __restrict__ outp) {
  __shared__ float Qs[8][33];
  __shared__ float Ks[64][33];
  __shared__ float Sc[8][1025];
  __shared__ float inv_den[8];
  const int qc = blockIdx.x;
  const int h = blockIdx.y;
  const int b = blockIdx.z;
  const int tid = threadIdx.x;
  const size_t rowbase = (size_t)(b * NQT) * DM + h * DHSA;
  {
    int r = tid >> 5, d = tid & 31;
    Qs[r][d] = qh[rowbase + (size_t)(qc * 8 + r) * DM + d];
  }
  const float scale = 0.17677669529663687f;  // 1/sqrt(32)
  for (int jt = 0; jt < 16; jt++) {
    __syncthreads();
#pragma unroll
    for (int i = 0; i < 8; i++) {
      int e = tid + i * 256;
      int j = e >> 5, d = e & 31;
      Ks[j][d] = kh[rowbase + (size_t)(jt * 64 + j) * DM + d];
    }
    __syncthreads();
    int r = tid >> 5, jj = tid & 31;
#pragma unroll
    for (int j2 = 0; j2 < 2; j2++) {
      int j = jj * 2 + j2;
      float s = 0.f;
#pragma unroll
      for (int d = 0; d < 32; d++) s = fmaf(Qs[r][d], Ks[j][d], s);
      Sc[r][jt * 64 + j] = s * scale;
    }
  }
  __syncthreads();
  {
    int r = tid >> 5, l = tid & 31;
    float m = -1e30f;
    for (int j = l; j < 1024; j += 32) m = fmaxf(m, Sc[r][j]);
#pragma unroll
    for (int o = 16; o >= 1; o >>= 1) m = fmaxf(m, __shfl_xor(m, o, 32));
    float sum = 0.f;
    for (int j = l; j < 1024; j += 32) {
      float p = expf(Sc[r][j] - m);
      Sc[r][j] = p;
      sum += p;
    }
#pragma unroll
    for (int o = 16; o >= 1; o >>= 1) sum += __shfl_xor(sum, o, 32);
    if (l == 0) inv_den[r] = 1.0f / sum;
  }
  const int r = tid >> 5, d = tid & 31;
  float acc = 0.f;
  for (int jt = 0; jt < 16; jt++) {
    __syncthreads();
#pragma unroll
    for (int i = 0; i < 8; i++) {
      int e = tid + i * 256;
      int j = e >> 5, dd = e & 31;
      Ks[j][dd] = vh[rowbase + (size_t)(jt * 64 + j) * DM + dd];
    }
    __syncthreads();
#pragma unroll 8
    for (int j = 0; j < 64; j++) acc = fmaf(Sc[r][jt * 64 + j], Ks[j][d], acc);
  }
  acc *= inv_den[r];
  outp[rowbase + (size_t)(qc * 8 + r) * DM + d] = acc;
}

// ---------------------------------------------------------------------------
// ref = sigmoid(x1 @ Wref + bref), off = x1 @ Woff + boff  (per query row)
// ---------------------------------------------------------------------------
__global__ __launch_bounds__(128) void refoff_k(
    const float* __restrict__ x1, const float* __restrict__ Wref,
    const float* __restrict__ bref, const float* __restrict__ Woff,
    const float* __restrict__ boff, float* __restrict__ refb,
    float* __restrict__ offb) {
  __shared__ float xs[256];
  const int row = blockIdx.x;
  const int tid = threadIdx.x;
  xs[tid] = x1[(size_t)row * DM + tid];
  xs[tid + 128] = x1[(size_t)row * DM + tid + 128];
  __syncthreads();
  if (tid < 3) {
    float s = bref[tid];
    for (int d = 0; d < 256; d++) s = fmaf(xs[d], Wref[d * 3 + tid], s);
    refb[(size_t)row * 3 + tid] = 1.0f / (1.0f + expf(-s));
  } else if (tid < 99) {
    int o = tid - 3;
    float s = boff[o];
    for (int d = 0; d < 256; d++) s = fmaf(xs[d], Woff[d * 96 + o], s);
    offb[(size_t)row * 96 + o] = s;
  }
}

// ---------------------------------------------------------------------------
// Shared trilinear corner computation for one (bn, h).
// ---------------------------------------------------------------------------
__device__ __forceinline__ void calc_corners(
    const float* __restrict__ refb, const float* __restrict__ offb, int bn,
    int h, int (&idxs)[NPT][8], float (&wts)[NPT][8]) {
  const float rt = refb[bn * 3 + 0], ry = refb[bn * 3 + 1], rx = refb[bn * 3 + 2];
  const float* ofp = &offb[(size_t)bn * 96 + h * 12];
#pragma unroll
  for (int p = 0; p < NPT; p++) {
    float lt = rt + ofp[p * 3 + 0] * 0.5f;      // OFFSET_SCALE / T
    float ly = ry + ofp[p * 3 + 1] * 0.03125f;  // OFFSET_SCALE / H
    float lx = rx + ofp[p * 3 + 2] * 0.03125f;  // OFFSET_SCALE / W
    float pt = fminf(fmaxf(lt, 0.f), 1.f) * (TT - 1);
    float py = fminf(fmaxf(ly, 0.f), 1.f) * (HH - 1);
    float px = fminf(fmaxf(lx, 0.f), 1.f) * (WW - 1);
    float f0t = floorf(pt), f0y = floorf(py), f0x = floorf(px);
    float frt = pt - f0t, fry = py - f0y, frx = px - f0x;
    int t0 = (int)f0t, y0 = (int)f0y, x0 = (int)f0x;
    int t1 = min(t0 + 1, TT - 1), y1 = min(y0 + 1, HH - 1), x1 = min(x0 + 1, WW - 1);
    float wt0 = 1.f - frt, wy0 = 1.f - fry, wx0 = 1.f - frx;
#pragma unroll
    for (int c = 0; c < 8; c++) {
      int dt = c >> 2, dy = (c >> 1) & 1, dx = c & 1;
      int ct = dt ? t1 : t0, cy = dy ? y1 : y0, cx = dx ? x1 : x0;
      idxs[p][c] = ct * (HH * WW) + cy * WW + cx;
      wts[p][c] = (dt ? frt : wt0) * (dy ? fry : wy0) * (dx ? frx : wx0);
    }
  }
}

// ---------------------------------------------------------------------------
// Sample k-volume at the 4 points, dot with q -> 4 logits into slots.
// One wave per (b,n,h); lane = channel.
// ---------------------------------------------------------------------------
__global__ __launch_bounds__(256) void ca_logits_k(
    const float* __restrict__ qh, const float* __restrict__ refb,
    const float* __restrict__ offb, const bf16* __restrict__ vol,
    float* __restrict__ logits, int slot) {
  const int wid = (blockIdx.x * blockDim.x + threadIdx.x) >> 6;  // 0..32767
  const int lane = threadIdx.x & 63;
  const int h = wid & 7;
  const int bn = wid >> 3;  // 0..4095
  const int b = bn >> 10;
  const float q = qh[(size_t)bn * CAI + h * CADH + lane];
  int idxs[NPT][8];
  float wts[NPT][8];
  calc_corners(refb, offb, bn, h, idxs, wts);
  const size_t volbase = (size_t)b * LVOL * CAI + h * CADH + lane;
  float* lp = logits + ((size_t)bn * CAH + h) * 8 + slot;
#pragma unroll
  for (int p = 0; p < NPT; p++) {
    float ks = 0.f;
#pragma unroll
    for (int c = 0; c < 8; c++)
      ks = fmaf(wts[p][c], b2f(vol[volbase + (size_t)idxs[p][c] * CAI]), ks);
    float li = wave_sum64(q * ks) * 0.125f;  // 1/sqrt(64)
    if (lane == p) lp[p] = li;
  }
}

// ---------------------------------------------------------------------------
// Joint softmax over the 8 logits (4 img + 4 flow) per (bn, h), in place.
// ---------------------------------------------------------------------------
__global__ __launch_bounds__(256) void ca_softmax_k(float* __restrict__ logits) {
  const int i = blockIdx.x * blockDim.x + threadIdx.x;  // 0..32767
  float* p = logits + (size_t)i * 8;
  float v[8], m = -1e30f;
#pragma unroll
  for (int j = 0; j < 8; j++) { v[j] = p[j]; m = fmaxf(m, v[j]); }
  float s = 0.f;
#pragma unroll
  for (int j = 0; j < 8; j++) { v[j] = expf(v[j] - m); s += v[j]; }
  const float inv = 1.0f / s;
#pragma unroll
  for (int j = 0; j < 8; j++) p[j] = v[j] * inv;
}

// ---------------------------------------------------------------------------
// Sample v-volume, weight by attn slots, accumulate into f32 acc.
// ---------------------------------------------------------------------------
template <int FIRST>
__global__ __launch_bounds__(256) void ca_acc_k(
    const float* __restrict__ refb, const float* __restrict__ offb,
    const bf16* __restrict__ vol, const float* __restrict__ attn,
    float* __restrict__ acc, int slot) {
  const int wid = (blockIdx.x * blockDim.x + threadIdx.x) >> 6;
  const int lane = threadIdx.x & 63;
  const int h = wid & 7;
  const int bn = wid >> 3;
  const int b = bn >> 10;
  int idxs[NPT][8];
  float wts[NPT][8];
  calc_corners(refb, offb, bn, h, idxs, wts);
  const size_t volbase = (size_t)b * LVOL * CAI + h * CADH + lane;
  const float* ap = attn + ((size_t)bn * CAH + h) * 8 + slot;
  const size_t off = (size_t)bn * CAI + h * CADH + lane;
  float a = FIRST ? 0.f : acc[off];
#pragma unroll
  for (int p = 0; p < NPT; p++) {
    float vs = 0.f;
#pragma unroll
    for (int c = 0; c < 8; c++)
      vs = fmaf(wts[p][c], b2f(vol[volbase + (size_t)idxs[p][c] * CAI]), vs);
    a = fmaf(ap[p], vs, a);
  }
  acc[off] = a;
}

// ---------------------------------------------------------------------------
// LayerNorm over 256 dims of (res + x); one wave per row; f32 in/out.
// ---------------------------------------------------------------------------
__global__ __launch_bounds__(256) void ln_k(
    const float* __restrict__ resv, const float* __restrict__ x,
    const float* __restrict__ g, const float* __restrict__ bb,
    float* __restrict__ of) {
  const int row = (blockIdx.x * blockDim.x + threadIdx.x) >> 6;
  const int lane = threadIdx.x & 63;
  const size_t base = (size_t)row * DM;
  float v[4];
#pragma unroll
  for (int i = 0; i < 4; i++) {
    int d = lane + i * 64;
    v[i] = resv[base + d] + x[base + d];
  }
  float s = wave_sum64(v[0] + v[1] + v[2] + v[3]);
  const float mean = s * (1.0f / 256.0f);
  float vs = 0.f;
#pragma unroll
  for (int i = 0; i < 4; i++) { float d0 = v[i] - mean; vs = fmaf(d0, d0, vs); }
  vs = wave_sum64(vs);
  const float rstd = rsqrtf(vs * (1.0f / 256.0f) + 1e-5f);
#pragma unroll
  for (int i = 0; i < 4; i++) {
    int d = lane + i * 64;
    of[base + d] = (v[i] - mean) * rstd * g[d] + bb[d];
  }
}

extern "C" void kernel_launch(void* const* d_in, const int* in_sizes, int n_in,
                              void* d_out, int out_size, void* d_ws,
                              size_t ws_size, hipStream_t stream) {
  const float* query = (const float*)d_in[0];
  const float* qpos = (const float*)d_in[1];
  const float* img = (const float*)d_in[2];
  const float* flow = (const float*)d_in[3];
  const float* pos = (const float*)d_in[4];
  const float* sa_Wq = (const float*)d_in[6];
  const float* sa_Wk = (const float*)d_in[7];
  const float* sa_Wv = (const float*)d_in[8];
  const float* sa_Wo = (const float*)d_in[9];
  const float* sa_bq = (const float*)d_in[10];
  const float* sa_bk = (const float*)d_in[11];
  const float* sa_bv = (const float*)d_in[12];
  const float* sa_bo = (const float*)d_in[13];
  const float* ln1_b = (const float*)d_in[14];
  const float* ln2_b = (const float*)d_in[15];
  const float* ln3_b = (const float*)d_in[16];
  const float* ln1_g = (const float*)d_in[17];
  const float* ln2_g = (const float*)d_in[18];
  const float* ln3_g = (const float*)d_in[19];
  const float* ca_Wq = (const float*)d_in[20];
  const float* ca_bq = (const float*)d_in[21];
  const float* ca_Wk = (const float*)d_in[22];
  const float* ca_bk = (const float*)d_in[23];
  const float* ca_Wv = (const float*)d_in[24];
  const float* ca_bv = (const float*)d_in[25];
  const float* ca_Wref = (const float*)d_in[26];
  const float* ca_bref = (const float*)d_in[27];
  const float* ca_Woff = (const float*)d_in[28];
  const float* ca_boff = (const float*)d_in[29];
  const float* ca_Wo = (const float*)d_in[30];
  const float* ca_bo = (const float*)d_in[31];
  const float* ffn_W1 = (const float*)d_in[32];
  const float* ffn_b1 = (const float*)d_in[33];
  const float* ffn_W2 = (const float*)d_in[34];
  const float* ffn_b2 = (const float*)d_in[35];

  const int MQ = BQ * NQT;   // 4096
  const int MV = BQ * LVOL;  // 65536
  const size_t MB = 1024 * 1024;

  char* r0 = (char*)d_ws;  // 64 MB time-shared region
  char* w = r0 + 64 * MB;
  auto alloc = [&](size_t n) {
    char* p = w;
    w += (n + 255) & ~(size_t)255;
    return p;
  };
  float* x1_f = (float*)alloc((size_t)MQ * DM * 4);
  float* ca_qh = (float*)alloc((size_t)MQ * CAI * 4);
  float* refb = (float*)alloc((size_t)MQ * 3 * 4);
  float* offb = (float*)alloc((size_t)MQ * 96 * 4);
  float* logits = (float*)alloc((size_t)MQ * CAH * 8 * 4);
  float* ca_acc = (float*)alloc((size_t)MQ * CAI * 4);
  // transposed bf16 weights [N][K]
  short* WtsaQ = (short*)alloc((size_t)DM * DM * 2);
  short* WtsaK = (short*)alloc((size_t)DM * DM * 2);
  short* WtsaV = (short*)alloc((size_t)DM * DM * 2);
  short* WtsaO = (short*)alloc((size_t)DM * DM * 2);
  short* Wtcaq = (short*)alloc((size_t)CAI * DM * 2);
  short* Wtk = (short*)alloc((size_t)CAI * DM * 2);
  short* Wtv = (short*)alloc((size_t)CAI * DM * 2);
  short* Wtcao = (short*)alloc((size_t)DM * CAI * 2);
  short* Wtf1 = (short*)alloc((size_t)DFFN * DM * 2);
  short* Wtf2 = (short*)alloc((size_t)DM * DFFN * 2);
  if ((size_t)(w - (char*)d_ws) > ws_size) return;  // graceful fail (diagnostic)

  // SA-phase overlays in region0 (all f32 now)
  float* qh_sa = (float*)(r0 + 0 * MB);
  float* kh_sa = (float*)(r0 + 4 * MB);
  float* vh_sa = (float*)(r0 + 8 * MB);
  float* sa_att = (float*)(r0 + 12 * MB);
  float* sa_proj = (float*)(r0 + 16 * MB);
  // CA volume overlay
  bf16* vol = (bf16*)r0;  // 64 MB
  // post-CA overlays
  float* ca_o = (float*)(r0 + 0 * MB);
  float* x2_f = (float*)(r0 + 4 * MB);
  float* ffn_h = (float*)(r0 + 8 * MB);   // 16 MB
  float* ffn_o = (float*)(r0 + 24 * MB);

  dim3 blk(256);
  // --- weight transposes (bf16 cast) ---
  wtrans_k<8><<<dim3(DM * DM / 256), blk, 0, stream>>>(sa_Wq, WtsaQ, DM);
  wtrans_k<8><<<dim3(DM * DM / 256), blk, 0, stream>>>(sa_Wk, WtsaK, DM);
  wtrans_k<8><<<dim3(DM * DM / 256), blk, 0, stream>>>(sa_Wv, WtsaV, DM);
  wtrans_k<8><<<dim3(DM * DM / 256), blk, 0, stream>>>(sa_Wo, WtsaO, DM);
  wtrans_k<8><<<dim3(DM * CAI / 256), blk, 0, stream>>>(ca_Wq, Wtcaq, CAI);
  wtrans_k<8><<<dim3(DM * CAI / 256), blk, 0, stream>>>(ca_Wk, Wtk, CAI);
  wtrans_k<8><<<dim3(DM * CAI / 256), blk, 0, stream>>>(ca_Wv, Wtv, CAI);
  wtrans_k<8><<<dim3(DM * DFFN / 256), blk, 0, stream>>>(ffn_W1, Wtf1, DFFN);
  wtrans_k<9><<<dim3(CAI * DM / 256), blk, 0, stream>>>(ca_Wo, Wtcao, DM);
  wtrans_k<10><<<dim3(DFFN * DM / 256), blk, 0, stream>>>(ffn_W2, Wtf2, DM);
  // --- self-attention ---
  mgemm_k<1, 0, 0><<<dim3(DM / 128, MQ / 128), blk, 0, stream>>>(query, qpos, WtsaQ, sa_bq, (void*)qh_sa, MQ, DM, DM);
  mgemm_k<1, 0, 0><<<dim3(DM / 128, MQ / 128), blk, 0, stream>>>(query, qpos, WtsaK, sa_bk, (void*)kh_sa, MQ, DM, DM);
  mgemm_k<0, 0, 0><<<dim3(DM / 128, MQ / 128), blk, 0, stream>>>(query, query, WtsaV, sa_bv, (void*)vh_sa, MQ, DM, DM);
  sa_attn_k<<<dim3(128, 8, 4), blk, 0, stream>>>(qh_sa, kh_sa, vh_sa, sa_att);
  mgemm_k<0, 0, 0><<<dim3(DM / 128, MQ / 128), blk, 0, stream>>>(sa_att, sa_att, WtsaO, sa_bo, (void*)sa_proj, MQ, DM, DM);
  ln_k<<<dim3(MQ / 4), blk, 0, stream>>>(query, sa_proj, ln1_g, ln1_b, x1_f);
  // --- deformable cross-attention (single shared volume buffer) ---
  mgemm_k<0, 0, 0><<<dim3(CAI / 128, MQ / 128), blk, 0, stream>>>(x1_f, x1_f, Wtcaq, ca_bq, (void*)ca_qh, MQ, CAI, DM);
  refoff_k<<<dim3(MQ), dim3(128), 0, stream>>>(x1_f, ca_Wref, ca_bref, ca_Woff, ca_boff, refb, offb);
  mgemm_k<1, 0, 1><<<dim3(CAI / 128, MV / 128), blk, 0, stream>>>(pos, img, Wtk, ca_bk, (void*)vol, MV, CAI, DM);
  ca_logits_k<<<dim3(8192), blk, 0, stream>>>(ca_qh, refb, offb, vol, logits, 0);
  mgemm_k<1, 0, 1><<<dim3(CAI / 128, MV / 128), blk, 0, stream>>>(pos, flow, Wtk, ca_bk, (void*)vol, MV, CAI, DM);
  ca_logits_k<<<dim3(8192), blk, 0, stream>>>(ca_qh, refb, offb, vol, logits, 4);
  ca_softmax_k<<<dim3(128), blk, 0, stream>>>(logits);
  mgemm_k<0, 0, 1><<<dim3(CAI / 128, MV / 128), blk, 0, stream>>>(img, img, Wtv, ca_bv, (void*)vol, MV, CAI, DM);
  ca_acc_k<1><<<dim3(8192), blk, 0, stream>>>(refb, offb, vol, logits, ca_acc, 0);
  mgemm_k<0, 0, 1><<<dim3(CAI / 128, MV / 128), blk, 0, stream>>>(flow, flow, Wtv, ca_bv, (void*)vol, MV, CAI, DM);
  ca_acc_k<0><<<dim3(8192), blk, 0, stream>>>(refb, offb, vol, logits, ca_acc, 4);
  mgemm_k<0, 0, 0><<<dim3(DM / 128, MQ / 128), blk, 0, stream>>>(ca_acc, ca_acc, Wtcao, ca_bo, (void*)ca_o, MQ, DM, CAI);
  ln_k<<<dim3(MQ / 4), blk, 0, stream>>>(x1_f, ca_o, ln2_g, ln2_b, x2_f);
  // --- FFN ---
  mgemm_k<0, 1, 0><<<dim3(DFFN / 128, MQ / 128), blk, 0, stream>>>(x2_f, x2_f, Wtf1, ffn_b1, (void*)ffn_h, MQ, DFFN, DM);
  mgemm_k<0, 0, 0><<<dim3(DM / 128, MQ / 128), blk, 0, stream>>>(ffn_h, ffn_h, Wtf2, ffn_b2, (void*)ffn_o, MQ, DM, DFFN);
  ln_k<<<dim3(MQ / 4), blk, 0, stream>>>(x2_f, ffn_o, ln3_g, ln3_b, (float*)d_out);
}